// Round 1
// baseline (27003.052 us; speedup 1.0000x reference)
//
#include <hip/hip_runtime.h>
#include <hip/hip_cooperative_groups.h>

namespace cg = cooperative_groups;

#define BB 64
#define TT 1024
#define DIN 128
#define NB 256
#define KW 5
#define HID 512
#define LL 510
#define LT 32
#define NREC_BLK 256
#define NREC_THR 512
#define EPS 1e-5f

// ---------------- Conv1d + ReLU + BatchNorm (eval) -> seq[L][B][NB] ----------------
// grid (16, 64): blockIdx.x = l-chunk, blockIdx.y = batch. 256 threads = one per filter.
__global__ __launch_bounds__(256) void conv_kernel(
    const float* __restrict__ x, const float* __restrict__ cw,
    const float* __restrict__ cb, const float* __restrict__ gma,
    const float* __restrict__ bta, const float* __restrict__ bmean,
    const float* __restrict__ bvar, float* __restrict__ seq)
{
  __shared__ float xt[2*LT+3][DIN];   // 67 x-rows of this chunk, 34.3 KB
  const int b = blockIdx.y, lc = blockIdx.x, tid = threadIdx.x;
  const int l0 = lc*LT, t0 = l0*2;

  const float4* x4 = (const float4*)(x + ((size_t)b*TT + t0)*DIN);
  for (int i = tid; i < (2*LT+3)*(DIN/4); i += 256) {
    const int r = i >> 5, c = i & 31;
    float4 v = make_float4(0.f, 0.f, 0.f, 0.f);
    if (t0 + r < TT) v = x4[(size_t)r*(DIN/4) + c];
    ((float4*)xt[r])[c] = v;
  }
  __syncthreads();

  const int f = tid;
  float acc[LT];
#pragma unroll
  for (int l = 0; l < LT; ++l) acc[l] = 0.f;

  const float* wr = cw + (size_t)f*(DIN*KW);
  for (int d = 0; d < DIN; ++d) {
    float xr[2*LT+3];                 // register-cache the x column for this d
#pragma unroll
    for (int r = 0; r < 2*LT+3; ++r) xr[r] = xt[r][d];
#pragma unroll
    for (int k = 0; k < KW; ++k) {
      const float w = wr[d*KW + k];
#pragma unroll
      for (int l = 0; l < LT; ++l) acc[l] += w * xr[2*l + k];
    }
  }

  const float bias  = cb[f];
  const float scale = gma[f] * rsqrtf(bvar[f] + EPS);
  const float shift = bta[f] - bmean[f]*scale;
#pragma unroll
  for (int l = 0; l < LT; ++l) {
    const int ll = l0 + l;
    if (ll < LL) {
      float y = acc[l] + bias;
      y = fmaxf(y, 0.f);
      seq[((size_t)ll*BB + b)*NB + f] = y*scale + shift;
    }
  }
}

// ---------------- SkipLSTM recurrence (cooperative, 1 grid.sync per step) ----------------
// 256 blocks: bg = blk>>6 (4 groups of 16 batches), js = blk&63 (64 slices of 8 hidden).
// 512 threads: q = tid>>5 (16 k-chunks), row = tid&31 (4 gates x 8 hidden rows).
// W_hh/W_ih rows live in REGISTERS for the whole kernel (48 floats/thread).
// Per step: stage h[16][512] + seq_t[16][256] in LDS -> partial dots -> shfl+LDS reduce
// -> activations -> c/h/u update -> write h & du-partials (double-buffered) -> grid.sync.
__global__ __launch_bounds__(NREC_THR, 2) void rec_kernel(
    const float* __restrict__ seq, const float* __restrict__ wih,
    const float* __restrict__ whh, const float* __restrict__ bih,
    const float* __restrict__ bhh, const float* __restrict__ wu,
    const float* __restrict__ bu, float* __restrict__ hbuf,
    float* __restrict__ dotp, float* __restrict__ out)
{
  cg::grid_group grid = cg::this_grid();

  __shared__ float h_lds[16][HID];    // 32 KB
  __shared__ float s_lds[16][NB];     // 16 KB
  __shared__ float part[8][16][32];   // 16 KB  (wave, batch, gate-row)
  __shared__ float gact[16][32];      // 2 KB   activated gates
  __shared__ float c_l[16][8];        // cell state (block-local, persists across steps)
  __shared__ float ut_l[16], u_l[16];

  const int tid = threadIdx.x;
  const int bg = blockIdx.x >> 6, js = blockIdx.x & 63;
  const int b0 = bg*16, j0 = js*8;
  const int q = tid >> 5, row = tid & 31;
  const int gi = row >> 3;                   // 0=i 1=f 2=g 3=o
  const int jj = row & 7;
  const int grow = gi*HID + j0 + jj;         // row in [4H]
  const int wv = tid >> 6;                   // wave index 0..7

  // ---- permanent weight registers ----
  float4 wh[8], wi4[4];
  {
    const float4* whr = (const float4*)(whh + (size_t)grow*HID) + q*8;
#pragma unroll
    for (int i = 0; i < 8; ++i) wh[i] = whr[i];
    const float4* wir = (const float4*)(wih + (size_t)grow*NB) + q*4;
#pragma unroll
    for (int i = 0; i < 4; ++i) wi4[i] = wir[i];
  }
  const float bias = bih[grow] + bhh[grow];
  const float wur  = wu[j0 + (tid & 7)];
  const float buv  = bu[0];

  if (tid < 16) { ut_l[tid] = 1.f; u_l[tid] = 1.f; }
  if (tid < 128) c_l[tid>>3][tid&7] = 0.f;
  __syncthreads();

  for (int t = 0; t < LL; ++t) {
    // ---- phase A: stage h, seq[t]; update ut/u from previous step's du-dot ----
    if (t > 0) {
      const float4* hr = (const float4*)(hbuf + (size_t)((t-1)&1)*BB*HID + (size_t)b0*HID);
      float4* hd = (float4*)h_lds;
      for (int i = tid; i < 16*HID/4; i += NREC_THR) hd[i] = hr[i];
      if (tid < 16) {
        const float4* dp4 = (const float4*)(dotp + (size_t)((t-1)&1)*BB*64 + (size_t)(b0+tid)*64);
        float s = 0.f;
#pragma unroll
        for (int i = 0; i < 16; ++i) { const float4 v = dp4[i]; s += v.x+v.y+v.z+v.w; }
        const float du  = 1.f/(1.f + expf(-(s + buv)));
        const float utv = ut_l[tid], up = u_l[tid];
        const float utn = up*du + (1.f-up)*(utv + fminf(du, 1.f-utv));
        ut_l[tid] = utn;
        u_l[tid]  = rintf(utn);      // round-half-even == jnp.round
      }
    }
    {
      const float4* sr = (const float4*)(seq + ((size_t)t*BB + b0)*NB);
      float4* sd = (float4*)s_lds;
      for (int i = tid; i < 16*NB/4; i += NREC_THR) sd[i] = sr[i];
    }
    __syncthreads();

    // ---- phase B: partial dots (weights in registers, h/s broadcast from LDS) ----
    {
      float accs[16];
      const float4* h4base = (const float4*)h_lds;
      const float4* s4base = (const float4*)s_lds;
      for (int b = 0; b < 16; ++b) {
        float a = 0.f;
        if (t > 0) {
          const float4* h4 = h4base + b*(HID/4) + q*8;
#pragma unroll
          for (int i = 0; i < 8; ++i) {
            const float4 hv = h4[i];
            a += wh[i].x*hv.x + wh[i].y*hv.y + wh[i].z*hv.z + wh[i].w*hv.w;
          }
        }
        const float4* s4 = s4base + b*(NB/4) + q*4;
#pragma unroll
        for (int i = 0; i < 4; ++i) {
          const float4 sv = s4[i];
          a += wi4[i].x*sv.x + wi4[i].y*sv.y + wi4[i].z*sv.z + wi4[i].w*sv.w;
        }
        accs[b] = a;
      }
#pragma unroll
      for (int b = 0; b < 16; ++b) {
        const float a = accs[b] + __shfl_xor(accs[b], 32);
        if ((tid & 32) == 0) part[wv][b][row] = a;
      }
    }
    __syncthreads();

    // ---- phase C1: reduce 8 wave-partials, add bias, activate ----
    {
      const int cb2 = tid >> 5, crow = tid & 31;
      float v = bias;                       // bias belongs to (tid&31) == crow
#pragma unroll
      for (int p = 0; p < 8; ++p) v += part[p][cb2][crow];
      gact[cb2][crow] = ((crow >> 3) == 2) ? tanhf(v) : 1.f/(1.f + expf(-v));
    }
    __syncthreads();

    // ---- phase C2: state update for (16 batches x 8 hidden) ----
    if (tid < 128) {
      const int b = tid >> 3, j = tid & 7;
      const float ig = gact[b][j],     fg = gact[b][8+j];
      const float gg = gact[b][16+j],  og = gact[b][24+j];
      const float cold = c_l[b][j], u = u_l[b];
      const float cnew = fg*cold + ig*gg;
      const float ct   = u*cnew + (1.f-u)*cold;
      const float hold = (t > 0) ? h_lds[b][j0+j] : 0.f;
      const float ht   = u*(og*tanhf(ct)) + (1.f-u)*hold;
      c_l[b][j] = ct;
      hbuf[(size_t)(t&1)*BB*HID + (size_t)(b0+b)*HID + j0 + j] = ht;
      float p = ct * wur;                 // partial of c_t . w_u
      p += __shfl_xor(p, 1, 8);
      p += __shfl_xor(p, 2, 8);
      p += __shfl_xor(p, 4, 8);
      if (j == 0) dotp[(size_t)(t&1)*BB*64 + (size_t)(b0+b)*64 + js] = p;
      if (t == LL-1) out[(size_t)(b0+b)*HID + j0 + j] = ht;
    }
    grid.sync();
  }
}

extern "C" void kernel_launch(void* const* d_in, const int* in_sizes, int n_in,
                              void* d_out, int out_size, void* d_ws, size_t ws_size,
                              hipStream_t stream) {
  const float* x    = (const float*)d_in[0];
  const float* cw   = (const float*)d_in[1];
  const float* cb   = (const float*)d_in[2];
  const float* gma  = (const float*)d_in[3];
  const float* bta  = (const float*)d_in[4];
  const float* bmean= (const float*)d_in[5];
  const float* bvar = (const float*)d_in[6];
  const float* wih  = (const float*)d_in[7];
  const float* whh  = (const float*)d_in[8];
  const float* bih  = (const float*)d_in[9];
  const float* bhh  = (const float*)d_in[10];
  const float* wu   = (const float*)d_in[11];
  const float* bu   = (const float*)d_in[12];
  float* out = (float*)d_out;

  float* ws   = (float*)d_ws;
  float* seq  = ws;                                  // L*B*NB      = 8,355,840 f
  float* hbuf = seq  + (size_t)LL*BB*NB;             // 2*B*HID     = 65,536 f
  float* dotp = hbuf + (size_t)2*BB*HID;             // 2*B*64      = 8,192 f

  hipLaunchKernelGGL(conv_kernel, dim3(16, 64), dim3(256), 0, stream,
                     x, cw, cb, gma, bta, bmean, bvar, seq);

  void* args[] = { (void*)&seq, (void*)&wih, (void*)&whh, (void*)&bih, (void*)&bhh,
                   (void*)&wu, (void*)&bu, (void*)&hbuf, (void*)&dotp, (void*)&out };
  hipLaunchCooperativeKernel(rec_kernel, dim3(NREC_BLK), dim3(NREC_THR),
                             args, 0, stream);
}